// Round 1
// baseline (1449.292 us; speedup 1.0000x reference)
//
#include <hip/hip_runtime.h>

// ---------------------------------------------------------------------------
// Int4 dequant-linear: out[b,s,o] = sum_k x[b,s,k] * (nib(q[o,k]) * scale[o]) + bias[o]
// M = B*S = 8192, K = 4096, N = 11008. fp16 MFMA GEMM with inline dequant.
// Scale is applied in the epilogue (B frags carry exact int values in fp16).
// ---------------------------------------------------------------------------

typedef _Float16 half8 __attribute__((ext_vector_type(8)));
typedef float    floatx4 __attribute__((ext_vector_type(4)));
typedef float    fvec4 __attribute__((ext_vector_type(4)));
typedef int      ivec4 __attribute__((ext_vector_type(4)));

constexpr int M_TOT   = 8192;
constexpr int N_TOT   = 11008;
constexpr int K_TOT   = 4096;
constexpr int PACKEDC = 2048;   // int32 entries per qweight row (1 byte each)
constexpr int LDSS    = 40;     // LDS row stride in halfs (80 B: 16B-aligned, 2-way banks = free)

__global__ __launch_bounds__(256, 2)
void int4lin_kernel(const float* __restrict__ X,
                    const int*   __restrict__ Q,
                    const float* __restrict__ scale,
                    const float* __restrict__ bias,
                    float*       __restrict__ out)
{
    __shared__ _Float16 As[2][128][LDSS];
    __shared__ _Float16 Bs[2][128][LDSS];

    const int tid  = threadIdx.x;
    const int lane = tid & 63;
    const int bx   = blockIdx.x;          // N tile (0..85)
    const int by   = blockIdx.y;          // M tile (0..63)
    const int wave = tid >> 6;
    const int wm   = (wave >> 1) * 64;    // wave's M offset in tile
    const int wn   = (wave & 1) * 64;     // wave's N offset in tile
    const int fr   = lane & 15;
    const int kg   = lane >> 4;           // 0..3

    // staging assignment: 2 threads per row; each thread stages 16 K-elems
    const int srow  = tid >> 1;           // 0..127
    const int shalf = tid & 1;            // 0..1

    const float* aptr = X + (size_t)(by * 128 + srow) * K_TOT + shalf * 16;
    const int*   bptr = Q + (size_t)(bx * 128 + srow) * PACKEDC + shalf * 8;

    floatx4 acc[4][4];
    #pragma unroll
    for (int i = 0; i < 4; ++i)
        #pragma unroll
        for (int j = 0; j < 4; ++j)
            acc[i][j] = (floatx4)0.0f;

    fvec4 araw[4];
    ivec4 braw[2];

    auto gload = [&](int kt) {
        const fvec4* ap = (const fvec4*)(aptr + (size_t)kt * 32);
        #pragma unroll
        for (int i = 0; i < 4; ++i) araw[i] = ap[i];
        const ivec4* bp = (const ivec4*)(bptr + kt * 16);
        #pragma unroll
        for (int i = 0; i < 2; ++i) braw[i] = bp[i];
    };

    auto cvt_write = [&](int buf) {
        // A: 16 fp32 -> 16 fp16
        #pragma unroll
        for (int v = 0; v < 2; ++v) {
            half8 h;
            #pragma unroll
            for (int e = 0; e < 8; ++e)
                h[e] = (_Float16)araw[v * 2 + (e >> 2)][e & 3];
            *(half8*)&As[buf][srow][shalf * 16 + v * 8] = h;
        }
        // B: 8 bytes -> 16 int4 nibbles -> fp16 (exact). low nibble = even k.
        #pragma unroll
        for (int v = 0; v < 2; ++v) {
            half8 h;
            #pragma unroll
            for (int e = 0; e < 4; ++e) {
                const int b = braw[v][e];            // in [0, 256)
                h[2 * e]     = (_Float16)((b & 15) - 8);
                h[2 * e + 1] = (_Float16)((b >> 4) - 8);
            }
            *(half8*)&Bs[buf][srow][shalf * 16 + v * 8] = h;
        }
    };

    gload(0);
    cvt_write(0);
    __syncthreads();

    int cur = 0;
    #pragma unroll 1
    for (int kt = 0; kt < K_TOT / 32; ++kt) {
        if (kt + 1 < K_TOT / 32) gload(kt + 1);   // issue prefetch early

        half8 af[4], bf[4];
        #pragma unroll
        for (int mi = 0; mi < 4; ++mi)
            af[mi] = *(const half8*)&As[cur][wm + mi * 16 + fr][kg * 8];
        #pragma unroll
        for (int ni = 0; ni < 4; ++ni)
            bf[ni] = *(const half8*)&Bs[cur][wn + ni * 16 + fr][kg * 8];

        #pragma unroll
        for (int mi = 0; mi < 4; ++mi)
            #pragma unroll
            for (int ni = 0; ni < 4; ++ni)
                acc[mi][ni] = __builtin_amdgcn_mfma_f32_16x16x32_f16(
                    af[mi], bf[ni], acc[mi][ni], 0, 0, 0);

        if (kt + 1 < K_TOT / 32) cvt_write(cur ^ 1);
        __syncthreads();
        cur ^= 1;
    }

    // epilogue: out = acc * scale[col] + bias[col]
    #pragma unroll
    for (int ni = 0; ni < 4; ++ni) {
        const int col = bx * 128 + wn + ni * 16 + fr;
        const float s  = scale[col];
        const float bv = bias[col];
        #pragma unroll
        for (int mi = 0; mi < 4; ++mi) {
            const int row0 = by * 128 + wm + mi * 16 + kg * 4;
            #pragma unroll
            for (int j = 0; j < 4; ++j)
                out[(size_t)(row0 + j) * N_TOT + col] = acc[mi][ni][j] * s + bv;
        }
    }
}

extern "C" void kernel_launch(void* const* d_in, const int* in_sizes, int n_in,
                              void* d_out, int out_size, void* d_ws, size_t ws_size,
                              hipStream_t stream) {
    const float* x     = (const float*)d_in[0];
    const int*   q     = (const int*)d_in[1];
    const float* scale = (const float*)d_in[2];
    const float* bias  = (const float*)d_in[3];
    float*       out   = (float*)d_out;

    dim3 grid(N_TOT / 128, M_TOT / 128);
    int4lin_kernel<<<grid, dim3(256), 0, stream>>>(x, q, scale, bias, out);
}

// Round 2
// 1065.847 us; speedup vs baseline: 1.3598x; 1.3598x over previous
//
#include <hip/hip_runtime.h>

// ---------------------------------------------------------------------------
// Int4 dequant-linear, two-phase:
//   1) prepass: X fp32 -> fp16 (64 MB), Q int4-in-int32 -> fp16 ints (90 MB), both in d_ws
//   2) fp16 MFMA GEMM (m97 structure: global_load_lds width 16, dbuf LDS, BK=64),
//      scale/bias applied in epilogue.
// Band-16 M-fastest rasterization for L2/L3 locality (fixes the 5.3 GB over-fetch).
// Fallback to the round-1 fused kernel if ws is too small.
// ---------------------------------------------------------------------------

typedef _Float16 half8 __attribute__((ext_vector_type(8)));
typedef _Float16 h2    __attribute__((ext_vector_type(2)));
typedef float    floatx4 __attribute__((ext_vector_type(4)));
typedef float    fvec4 __attribute__((ext_vector_type(4)));
typedef int      ivec4 __attribute__((ext_vector_type(4)));

constexpr int M_TOT   = 8192;
constexpr int N_TOT   = 11008;
constexpr int K_TOT   = 4096;
constexpr int PACKEDC = 2048;
constexpr size_t XF_BYTES = (size_t)M_TOT * K_TOT * 2;   // 64 MiB
constexpr size_t WF_BYTES = (size_t)N_TOT * K_TOT * 2;   // ~86 MiB

// ---------------- prepass: X fp32 -> fp16 ----------------
__global__ void cvt_x_kernel(const float* __restrict__ x, _Float16* __restrict__ xf, int n8) {
    const int stride = gridDim.x * blockDim.x;
    for (int i = blockIdx.x * blockDim.x + threadIdx.x; i < n8; i += stride) {
        const fvec4* p = (const fvec4*)(x + (size_t)i * 8);
        fvec4 a = p[0], b = p[1];
        half8 h;
        #pragma unroll
        for (int j = 0; j < 4; ++j) { h[j] = (_Float16)a[j]; h[4 + j] = (_Float16)b[j]; }
        *(half8*)(xf + (size_t)i * 8) = h;
    }
}

// ---------------- prepass: Q nibbles -> fp16 (exact ints, scale deferred) ----------------
__global__ void cvt_q_kernel(const int* __restrict__ q, _Float16* __restrict__ wf, int n4) {
    const int stride = gridDim.x * blockDim.x;
    for (int i = blockIdx.x * blockDim.x + threadIdx.x; i < n4; i += stride) {
        ivec4 d = ((const ivec4*)q)[i];
        half8 h;
        #pragma unroll
        for (int e = 0; e < 4; ++e) {
            unsigned b = (unsigned)d[e];
            // lo16 = 1024 + lownib, hi16 = 1024 + highnib (fp16 bit trick), then -1032 -> nib-8
            unsigned u = ((b | (b << 12)) & 0x000F000Fu) | 0x64006400u;
            h2 v = __builtin_bit_cast(h2, u) - (_Float16)1032.0f;
            h[2 * e]     = v[0];
            h[2 * e + 1] = v[1];
        }
        *(half8*)(wf + (size_t)i * 8) = h;
    }
}

// ---------------- main fp16 GEMM (128x128 tile, BK=64, gload_lds, dbuf) ----------------
__global__ __launch_bounds__(256, 2)
void gemm_f16_kernel(const _Float16* __restrict__ A, const _Float16* __restrict__ Bm,
                     const float* __restrict__ scale, const float* __restrict__ bias,
                     float* __restrict__ out)
{
    __shared__ _Float16 As[2][128 * 64];
    __shared__ _Float16 Bs[2][128 * 64];

    const int tid  = threadIdx.x;
    const int lane = tid & 63;
    const int wave = tid >> 6;

    // band-16, M-fastest rasterization: NT_M=64, NT_N=86, band = 16x86 = 1376 blocks
    const int lin  = blockIdx.x;
    const int band = lin / (16 * 86);
    const int r    = lin % (16 * 86);
    const int tm   = band * 16 + (r & 15);
    const int tn   = r >> 4;

    const int fr = lane & 15;
    const int kg = lane >> 4;
    const int wm = (wave >> 1) * 64;
    const int wn = (wave & 1) * 64;

    const _Float16* Ag = A  + (size_t)tm * 128 * K_TOT;
    const _Float16* Bg = Bm + (size_t)tn * 128 * K_TOT;

    const int srow = lane >> 3;        // 0..7
    const int scol = (lane & 7) * 8;   // half index, 16B granules

    floatx4 acc[4][4];
    #pragma unroll
    for (int i = 0; i < 4; ++i)
        #pragma unroll
        for (int j = 0; j < 4; ++j)
            acc[i][j] = (floatx4)0.0f;

    auto stage = [&](int buf, int kt) {
        #pragma unroll
        for (int i = 0; i < 4; ++i) {
            const int row = wave * 32 + i * 8 + srow;
            const _Float16* ga = Ag + (size_t)row * K_TOT + kt * 64 + scol;
            const _Float16* gb = Bg + (size_t)row * K_TOT + kt * 64 + scol;
            _Float16* la = &As[buf][row * 64 + scol];
            _Float16* lb = &Bs[buf][row * 64 + scol];
            __builtin_amdgcn_global_load_lds((const __attribute__((address_space(1))) void*)ga,
                                             (__attribute__((address_space(3))) void*)la, 16, 0, 0);
            __builtin_amdgcn_global_load_lds((const __attribute__((address_space(1))) void*)gb,
                                             (__attribute__((address_space(3))) void*)lb, 16, 0, 0);
        }
    };

    stage(0, 0);
    __syncthreads();

    int cur = 0;
    constexpr int NK = K_TOT / 64;
    #pragma unroll 1
    for (int kt = 0; kt < NK; ++kt) {
        if (kt + 1 < NK) stage(cur ^ 1, kt + 1);   // async prefetch into other buffer

        #pragma unroll
        for (int h = 0; h < 2; ++h) {
            half8 af[4], bf[4];
            #pragma unroll
            for (int mi = 0; mi < 4; ++mi)
                af[mi] = *(const half8*)&As[cur][(wm + mi * 16 + fr) * 64 + h * 32 + kg * 8];
            #pragma unroll
            for (int ni = 0; ni < 4; ++ni)
                bf[ni] = *(const half8*)&Bs[cur][(wn + ni * 16 + fr) * 64 + h * 32 + kg * 8];
            #pragma unroll
            for (int mi = 0; mi < 4; ++mi)
                #pragma unroll
                for (int ni = 0; ni < 4; ++ni)
                    acc[mi][ni] = __builtin_amdgcn_mfma_f32_16x16x32_f16(
                        af[mi], bf[ni], acc[mi][ni], 0, 0, 0);
        }

        __syncthreads();   // drains vmcnt too -> prefetched buffer complete
        cur ^= 1;
    }

    #pragma unroll
    for (int ni = 0; ni < 4; ++ni) {
        const int col = tn * 128 + wn + ni * 16 + fr;
        const float s  = scale[col];
        const float bv = bias[col];
        #pragma unroll
        for (int mi = 0; mi < 4; ++mi) {
            const int row0 = tm * 128 + wm + mi * 16 + kg * 4;
            #pragma unroll
            for (int j = 0; j < 4; ++j)
                out[(size_t)(row0 + j) * N_TOT + col] = acc[mi][ni][j] * s + bv;
        }
    }
}

// ---------------- fallback: round-1 fused kernel (known good) ----------------
constexpr int LDSS = 40;

__global__ __launch_bounds__(256, 2)
void int4lin_fused_kernel(const float* __restrict__ X,
                          const int*   __restrict__ Q,
                          const float* __restrict__ scale,
                          const float* __restrict__ bias,
                          float*       __restrict__ out)
{
    __shared__ _Float16 As[2][128][LDSS];
    __shared__ _Float16 Bs[2][128][LDSS];

    const int tid  = threadIdx.x;
    const int lane = tid & 63;
    const int bx   = blockIdx.x;
    const int by   = blockIdx.y;
    const int wave = tid >> 6;
    const int wm   = (wave >> 1) * 64;
    const int wn   = (wave & 1) * 64;
    const int fr   = lane & 15;
    const int kg   = lane >> 4;

    const int srow  = tid >> 1;
    const int shalf = tid & 1;

    const float* aptr = X + (size_t)(by * 128 + srow) * K_TOT + shalf * 16;
    const int*   bptr = Q + (size_t)(bx * 128 + srow) * PACKEDC + shalf * 8;

    floatx4 acc[4][4];
    #pragma unroll
    for (int i = 0; i < 4; ++i)
        #pragma unroll
        for (int j = 0; j < 4; ++j)
            acc[i][j] = (floatx4)0.0f;

    fvec4 araw[4];
    ivec4 braw[2];

    auto gload = [&](int kt) {
        const fvec4* ap = (const fvec4*)(aptr + (size_t)kt * 32);
        #pragma unroll
        for (int i = 0; i < 4; ++i) araw[i] = ap[i];
        const ivec4* bp = (const ivec4*)(bptr + kt * 16);
        #pragma unroll
        for (int i = 0; i < 2; ++i) braw[i] = bp[i];
    };

    auto cvt_write = [&](int buf) {
        #pragma unroll
        for (int v = 0; v < 2; ++v) {
            half8 h;
            #pragma unroll
            for (int e = 0; e < 8; ++e)
                h[e] = (_Float16)araw[v * 2 + (e >> 2)][e & 3];
            *(half8*)&As[buf][srow][shalf * 16 + v * 8] = h;
        }
        #pragma unroll
        for (int v = 0; v < 2; ++v) {
            half8 h;
            #pragma unroll
            for (int e = 0; e < 4; ++e) {
                const int b = braw[v][e];
                h[2 * e]     = (_Float16)((b & 15) - 8);
                h[2 * e + 1] = (_Float16)((b >> 4) - 8);
            }
            *(half8*)&Bs[buf][srow][shalf * 16 + v * 8] = h;
        }
    };

    gload(0);
    cvt_write(0);
    __syncthreads();

    int cur = 0;
    #pragma unroll 1
    for (int kt = 0; kt < K_TOT / 32; ++kt) {
        if (kt + 1 < K_TOT / 32) gload(kt + 1);

        half8 af[4], bf[4];
        #pragma unroll
        for (int mi = 0; mi < 4; ++mi)
            af[mi] = *(const half8*)&As[cur][wm + mi * 16 + fr][kg * 8];
        #pragma unroll
        for (int ni = 0; ni < 4; ++ni)
            bf[ni] = *(const half8*)&Bs[cur][wn + ni * 16 + fr][kg * 8];

        #pragma unroll
        for (int mi = 0; mi < 4; ++mi)
            #pragma unroll
            for (int ni = 0; ni < 4; ++ni)
                acc[mi][ni] = __builtin_amdgcn_mfma_f32_16x16x32_f16(
                    af[mi], bf[ni], acc[mi][ni], 0, 0, 0);

        if (kt + 1 < K_TOT / 32) cvt_write(cur ^ 1);
        __syncthreads();
        cur ^= 1;
    }

    #pragma unroll
    for (int ni = 0; ni < 4; ++ni) {
        const int col = bx * 128 + wn + ni * 16 + fr;
        const float s  = scale[col];
        const float bv = bias[col];
        #pragma unroll
        for (int mi = 0; mi < 4; ++mi) {
            const int row0 = by * 128 + wm + mi * 16 + kg * 4;
            #pragma unroll
            for (int j = 0; j < 4; ++j)
                out[(size_t)(row0 + j) * N_TOT + col] = acc[mi][ni][j] * s + bv;
        }
    }
}

extern "C" void kernel_launch(void* const* d_in, const int* in_sizes, int n_in,
                              void* d_out, int out_size, void* d_ws, size_t ws_size,
                              hipStream_t stream) {
    const float* x     = (const float*)d_in[0];
    const int*   q     = (const int*)d_in[1];
    const float* scale = (const float*)d_in[2];
    const float* bias  = (const float*)d_in[3];
    float*       out   = (float*)d_out;

    if (ws_size >= XF_BYTES + WF_BYTES) {
        _Float16* xf = (_Float16*)d_ws;
        _Float16* wf = (_Float16*)((char*)d_ws + XF_BYTES);
        cvt_x_kernel<<<2048, 256, 0, stream>>>(x, xf, M_TOT * K_TOT / 8);
        cvt_q_kernel<<<2048, 256, 0, stream>>>(q, wf, N_TOT * PACKEDC / 4);
        gemm_f16_kernel<<<(M_TOT / 128) * (N_TOT / 128), 256, 0, stream>>>(xf, wf, scale, bias, out);
    } else {
        dim3 grid(N_TOT / 128, M_TOT / 128);
        int4lin_fused_kernel<<<grid, dim3(256), 0, stream>>>(x, q, scale, bias, out);
    }
}

// Round 4
// 724.044 us; speedup vs baseline: 2.0017x; 1.4721x over previous
//
#include <hip/hip_runtime.h>

// ---------------------------------------------------------------------------
// Int4 dequant-linear, two-phase:
//   1) prepass: X fp32 -> fp16 (64 MB), Q nibbles -> fp16 exact ints (86 MB) in d_ws
//   2) 256x256 8-phase fp16 MFMA GEMM (T2 swizzle + T3/T4 counted vmcnt + T5 setprio),
//      scale/bias in epilogue.
// Round-4 fix: tail vmcnt ledger (clamp stage kt, never skip loads) + final vmcnt(0).
// ---------------------------------------------------------------------------

typedef _Float16 half8 __attribute__((ext_vector_type(8)));
typedef _Float16 h2    __attribute__((ext_vector_type(2)));
typedef float    floatx4 __attribute__((ext_vector_type(4)));
typedef float    fvec4 __attribute__((ext_vector_type(4)));
typedef int      ivec4 __attribute__((ext_vector_type(4)));

constexpr int M_TOT   = 8192;
constexpr int N_TOT   = 11008;
constexpr int K_TOT   = 4096;
constexpr int PACKEDC = 2048;
constexpr int NKT     = K_TOT / 64;     // 64 K-tiles of BK=64
constexpr size_t XF_BYTES = (size_t)M_TOT * K_TOT * 2;
constexpr size_t WF_BYTES = (size_t)N_TOT * K_TOT * 2;

#define MEMFENCE() asm volatile("" ::: "memory")
static __device__ __forceinline__ void bar() {
    MEMFENCE(); __builtin_amdgcn_s_barrier(); MEMFENCE();
}

// ---------------- prepass: X fp32 -> fp16 ----------------
__global__ void cvt_x_kernel(const float* __restrict__ x, _Float16* __restrict__ xf, int n8) {
    const int stride = gridDim.x * blockDim.x;
    for (int i = blockIdx.x * blockDim.x + threadIdx.x; i < n8; i += stride) {
        const fvec4* p = (const fvec4*)(x + (size_t)i * 8);
        fvec4 a = p[0], b = p[1];
        half8 h;
        #pragma unroll
        for (int j = 0; j < 4; ++j) { h[j] = (_Float16)a[j]; h[4 + j] = (_Float16)b[j]; }
        *(half8*)(xf + (size_t)i * 8) = h;
    }
}

// ---------------- prepass: Q nibbles -> fp16 (exact ints, scale deferred) ----------------
__global__ void cvt_q_kernel(const int* __restrict__ q, _Float16* __restrict__ wf, int n4) {
    const int stride = gridDim.x * blockDim.x;
    for (int i = blockIdx.x * blockDim.x + threadIdx.x; i < n4; i += stride) {
        ivec4 d = ((const ivec4*)q)[i];
        half8 h;
        #pragma unroll
        for (int e = 0; e < 4; ++e) {
            unsigned b = (unsigned)d[e];
            unsigned u = ((b | (b << 12)) & 0x000F000Fu) | 0x64006400u;
            h2 v = __builtin_bit_cast(h2, u) - (_Float16)1032.0f;
            h[2 * e]     = v[0];
            h[2 * e + 1] = v[1];
        }
        *(half8*)(wf + (size_t)i * 8) = h;
    }
}

// ---------------- 256x256 8-phase GEMM ----------------
__global__ __launch_bounds__(512, 2)
void gemm8p_kernel(const _Float16* __restrict__ A, const _Float16* __restrict__ Bm,
                   const float* __restrict__ scale, const float* __restrict__ bias,
                   float* __restrict__ out)
{
    // [slot][mat(0=A,1=B)][half][128*64 halfs], 128 KiB total
    __shared__ _Float16 L[2][2][2][128 * 64];

    const int tid  = threadIdx.x;
    const int lane = tid & 63;
    const int wave = tid >> 6;
    const int wr   = wave >> 2;    // 0..1  (M half of tile)
    const int wc   = wave & 3;     // 0..3  (N quarter)
    const int fr   = lane & 15;
    const int kg   = lane >> 4;

    // XCD-bijective swizzle (1376 % 8 == 0) + band-8 M-fastest raster
    const int bid  = blockIdx.x;
    const int swz  = (bid & 7) * 172 + (bid >> 3);
    const int band = swz / 344;            // 344 = 8*43
    const int rr   = swz % 344;
    const int tm   = band * 8 + (rr & 7);  // 0..31
    const int tn   = rr >> 3;              // 0..42

    const int srow = lane >> 3;            // row within 8-row stage group
    const int sg   = lane & 7;             // LDS granule
    const int sgk  = sg ^ srow;            // pre-swizzled global granule (T2, rule #21)

    const _Float16* Ag = A  + (size_t)(tm * 256) * K_TOT;
    const _Float16* Bg = Bm + (size_t)(tn * 256) * K_TOT;

    floatx4 acc[8][4];
    #pragma unroll
    for (int i = 0; i < 8; ++i)
        #pragma unroll
        for (int j = 0; j < 4; ++j)
            acc[i][j] = (floatx4)0.0f;

    // stage one 128x64 half-tile (all 8 waves, 2 x global_load_lds each, linear dest).
    // kt is CLAMPED, never skipped: keeps the per-wave vmcnt ledger identical in the
    // tail iterations (round-3 bug: skipping loads broke the vmcnt(4) guarantee and
    // let ph4/ph6 read un-landed B data in the last K-tile).
    auto stage = [&](int slot, int mat, int half, int kt) {
        if (kt >= NKT) kt = NKT - 1;   // harmless re-stage; target slot is never read again
        const _Float16* gb = mat ? Bg : Ag;
        #pragma unroll
        for (int i = 0; i < 2; ++i) {
            const int row = wave * 16 + i * 8 + srow;
            const _Float16* g = gb + (size_t)(half * 128 + row) * K_TOT + kt * 64 + sgk * 8;
            _Float16* l = &L[slot][mat][half][row * 64 + sg * 8];
            __builtin_amdgcn_global_load_lds((const __attribute__((address_space(1))) void*)g,
                                             (__attribute__((address_space(3))) void*)l, 16, 0, 0);
        }
    };

    half8 a0[4][2], a1[4][2], bb[2][2];

    auto ldA = [&](int slot, int mh, half8 (&d)[4][2]) {
        const char* base = (const char*)&L[slot][0][wr][0];
        #pragma unroll
        for (int m4 = 0; m4 < 4; ++m4)
            #pragma unroll
            for (int ks = 0; ks < 2; ++ks) {
                const int row = (mh * 4 + m4) * 16 + fr;
                const int off = row * 128 + ((ks * 64 + kg * 16) ^ ((fr & 7) << 4));
                d[m4][ks] = *(const half8*)(base + off);
            }
    };
    auto ldB = [&](int slot, int nh) {
        const char* base = (const char*)&L[slot][1][wc >> 1][0];
        #pragma unroll
        for (int n2 = 0; n2 < 2; ++n2)
            #pragma unroll
            for (int ks = 0; ks < 2; ++ks) {
                const int row = (wc & 1) * 64 + (nh * 2 + n2) * 16 + fr;
                const int off = row * 128 + ((ks * 64 + kg * 16) ^ ((fr & 7) << 4));
                bb[n2][ks] = *(const half8*)(base + off);
            }
    };
    auto mma = [&](int mh, int nh, half8 (&a)[4][2]) {
        __builtin_amdgcn_s_setprio(1);
        #pragma unroll
        for (int m4 = 0; m4 < 4; ++m4)
            #pragma unroll
            for (int n2 = 0; n2 < 2; ++n2)
                #pragma unroll
                for (int ks = 0; ks < 2; ++ks)
                    acc[mh * 4 + m4][nh * 2 + n2] = __builtin_amdgcn_mfma_f32_16x16x32_f16(
                        a[m4][ks], bb[n2][ks], acc[mh * 4 + m4][nh * 2 + n2], 0, 0, 0);
        __builtin_amdgcn_s_setprio(0);
    };

    // prologue: tile0 (A,B) + tile1 (A) = 6 half-tiles; wait for first 4 (tile0)
    stage(0, 0, 0, 0); stage(0, 0, 1, 0); stage(0, 1, 0, 0); stage(0, 1, 1, 0);
    stage(1, 0, 0, 1); stage(1, 0, 1, 1);
    asm volatile("s_waitcnt vmcnt(4)" ::: "memory");
    bar();

    #pragma unroll 1
    for (int it = 0; it < K_TOT / 128; ++it) {
        const int t1 = 2 * it + 1, t2 = 2 * it + 2, t3 = 2 * it + 3;
        // ph0: Q(0,0) of tile 2it (slot 0)
        ldA(0, 0, a0); ldB(0, 0); stage(1, 1, 0, t1);
        bar(); asm volatile("s_waitcnt lgkmcnt(0)" ::: "memory");
        mma(0, 0, a0); bar();
        // ph1: Q(1,0)
        ldA(0, 1, a1); stage(1, 1, 1, t1);
        bar(); asm volatile("s_waitcnt lgkmcnt(0)" ::: "memory");
        mma(1, 0, a1); bar();
        // ph2: Q(1,1)
        ldB(0, 1); stage(0, 0, 0, t2);
        bar(); asm volatile("s_waitcnt lgkmcnt(0)" ::: "memory");
        mma(1, 1, a1); bar();
        // ph3: Q(0,1); counted vmcnt before slot-1 reads
        stage(0, 0, 1, t2);
        bar();
        mma(0, 1, a0);
        asm volatile("s_waitcnt vmcnt(4)" ::: "memory");
        bar();
        // ph4: Q(0,0) of tile 2it+1 (slot 1)
        ldA(1, 0, a0); ldB(1, 0); stage(0, 1, 0, t2);
        bar(); asm volatile("s_waitcnt lgkmcnt(0)" ::: "memory");
        mma(0, 0, a0); bar();
        // ph5: Q(1,0)
        ldA(1, 1, a1); stage(0, 1, 1, t2);
        bar(); asm volatile("s_waitcnt lgkmcnt(0)" ::: "memory");
        mma(1, 0, a1); bar();
        // ph6: Q(1,1)
        ldB(1, 1); stage(1, 0, 0, t3);
        bar(); asm volatile("s_waitcnt lgkmcnt(0)" ::: "memory");
        mma(1, 1, a1); bar();
        // ph7: Q(0,1); counted vmcnt before next-iter slot-0 reads
        stage(1, 0, 1, t3);
        bar();
        mma(0, 1, a0);
        asm volatile("s_waitcnt vmcnt(4)" ::: "memory");
        bar();
    }

    // drain remaining async LDS-writes before epilogue / wave exit
    asm volatile("s_waitcnt vmcnt(0)" ::: "memory");

    // epilogue: out = acc * scale[col] + bias[col]
    #pragma unroll
    for (int ni = 0; ni < 4; ++ni) {
        const int col = tn * 256 + wc * 64 + ni * 16 + fr;
        const float s  = scale[col];
        const float bv = bias[col];
        #pragma unroll
        for (int mi = 0; mi < 8; ++mi) {
            const int row0 = tm * 256 + wr * 128 + mi * 16 + kg * 4;
            #pragma unroll
            for (int j = 0; j < 4; ++j)
                out[(size_t)(row0 + j) * N_TOT + col] = acc[mi][ni][j] * s + bv;
        }
    }
}

// ---------------- fallback: round-1 fused kernel (known good) ----------------
constexpr int LDSS = 40;

__global__ __launch_bounds__(256, 2)
void int4lin_fused_kernel(const float* __restrict__ X,
                          const int*   __restrict__ Q,
                          const float* __restrict__ scale,
                          const float* __restrict__ bias,
                          float*       __restrict__ out)
{
    __shared__ _Float16 As[2][128][LDSS];
    __shared__ _Float16 Bs[2][128][LDSS];

    const int tid  = threadIdx.x;
    const int lane = tid & 63;
    const int bx   = blockIdx.x;
    const int by   = blockIdx.y;
    const int wave = tid >> 6;
    const int wm   = (wave >> 1) * 64;
    const int wn   = (wave & 1) * 64;
    const int fr   = lane & 15;
    const int kg   = lane >> 4;

    const int srow  = tid >> 1;
    const int shalf = tid & 1;

    const float* aptr = X + (size_t)(by * 128 + srow) * K_TOT + shalf * 16;
    const int*   bptr = Q + (size_t)(bx * 128 + srow) * PACKEDC + shalf * 8;

    floatx4 acc[4][4];
    #pragma unroll
    for (int i = 0; i < 4; ++i)
        #pragma unroll
        for (int j = 0; j < 4; ++j)
            acc[i][j] = (floatx4)0.0f;

    fvec4 araw[4];
    ivec4 braw[2];

    auto gload = [&](int kt) {
        const fvec4* ap = (const fvec4*)(aptr + (size_t)kt * 32);
        #pragma unroll
        for (int i = 0; i < 4; ++i) araw[i] = ap[i];
        const ivec4* bp = (const ivec4*)(bptr + kt * 16);
        #pragma unroll
        for (int i = 0; i < 2; ++i) braw[i] = bp[i];
    };

    auto cvt_write = [&](int buf) {
        #pragma unroll
        for (int v = 0; v < 2; ++v) {
            half8 h;
            #pragma unroll
            for (int e = 0; e < 8; ++e)
                h[e] = (_Float16)araw[v * 2 + (e >> 2)][e & 3];
            *(half8*)&As[buf][srow][shalf * 16 + v * 8] = h;
        }
        #pragma unroll
        for (int v = 0; v < 2; ++v) {
            half8 h;
            #pragma unroll
            for (int e = 0; e < 4; ++e) {
                const int b = braw[v][e];
                h[2 * e]     = (_Float16)((b & 15) - 8);
                h[2 * e + 1] = (_Float16)((b >> 4) - 8);
            }
            *(half8*)&Bs[buf][srow][shalf * 16 + v * 8] = h;
        }
    };

    gload(0);
    cvt_write(0);
    __syncthreads();

    int cur = 0;
    #pragma unroll 1
    for (int kt = 0; kt < K_TOT / 32; ++kt) {
        if (kt + 1 < K_TOT / 32) gload(kt + 1);

        half8 af[4], bf[4];
        #pragma unroll
        for (int mi = 0; mi < 4; ++mi)
            af[mi] = *(const half8*)&As[cur][wm + mi * 16 + fr][kg * 8];
        #pragma unroll
        for (int ni = 0; ni < 4; ++ni)
            bf[ni] = *(const half8*)&Bs[cur][wn + ni * 16 + fr][kg * 8];

        #pragma unroll
        for (int mi = 0; mi < 4; ++mi)
            #pragma unroll
            for (int ni = 0; ni < 4; ++ni)
                acc[mi][ni] = __builtin_amdgcn_mfma_f32_16x16x32_f16(
                    af[mi], bf[ni], acc[mi][ni], 0, 0, 0);

        if (kt + 1 < K_TOT / 32) cvt_write(cur ^ 1);
        __syncthreads();
        cur ^= 1;
    }

    #pragma unroll
    for (int ni = 0; ni < 4; ++ni) {
        const int col = bx * 128 + wn + ni * 16 + fr;
        const float s  = scale[col];
        const float bv = bias[col];
        #pragma unroll
        for (int mi = 0; mi < 4; ++mi) {
            const int row0 = by * 128 + wm + mi * 16 + kg * 4;
            #pragma unroll
            for (int j = 0; j < 4; ++j)
                out[(size_t)(row0 + j) * N_TOT + col] = acc[mi][ni][j] * s + bv;
        }
    }
}

extern "C" void kernel_launch(void* const* d_in, const int* in_sizes, int n_in,
                              void* d_out, int out_size, void* d_ws, size_t ws_size,
                              hipStream_t stream) {
    const float* x     = (const float*)d_in[0];
    const int*   q     = (const int*)d_in[1];
    const float* scale = (const float*)d_in[2];
    const float* bias  = (const float*)d_in[3];
    float*       out   = (float*)d_out;

    if (ws_size >= XF_BYTES + WF_BYTES) {
        _Float16* xf = (_Float16*)d_ws;
        _Float16* wf = (_Float16*)((char*)d_ws + XF_BYTES);
        cvt_x_kernel<<<2048, 256, 0, stream>>>(x, xf, M_TOT * K_TOT / 8);
        cvt_q_kernel<<<2048, 256, 0, stream>>>(q, wf, N_TOT * PACKEDC / 4);
        gemm8p_kernel<<<(M_TOT / 256) * (N_TOT / 256), 512, 0, stream>>>(xf, wf, scale, bias, out);
    } else {
        dim3 grid(N_TOT / 128, M_TOT / 128);
        int4lin_fused_kernel<<<grid, dim3(256), 0, stream>>>(x, q, scale, bias, out);
    }
}